// Round 11
// baseline (320.380 us; speedup 1.0000x reference)
//
#include <hip/hip_runtime.h>

#define FDIM 128
#define NRBF 20
constexpr float CUTOFF_F = 5.0f;
constexpr float PI_F = 3.14159265358979323846f;

typedef _Float16 h2 __attribute__((ext_vector_type(2)));
typedef _Float16 half4 __attribute__((ext_vector_type(4)));
typedef float f32x4 __attribute__((ext_vector_type(4)));

__device__ __forceinline__ uint packh(float a, float b) {
  union { _Float16 h[2]; uint u; } x;
  x.h[0] = (_Float16)a;
  x.h[1] = (_Float16)b;
  return x.u;
}
__device__ __forceinline__ float h_lo(uint w) {
  union { uint u; _Float16 h[2]; } x;
  x.u = w;
  return (float)x.h[0];
}
__device__ __forceinline__ float h_hi(uint w) {
  union { uint u; _Float16 h[2]; } x;
  x.u = w;
  return (float)x.h[1];
}
__device__ __forceinline__ float dot2(uint cw, h2 w, float acc) {
#if __has_builtin(__builtin_amdgcn_fdot2)
  h2 c = __builtin_bit_cast(h2, cw);
  return __builtin_amdgcn_fdot2(c, w, acc, false);
#else
  return fmaf(h_hi(cw), (float)w[1], fmaf(h_lo(cw), (float)w[0], acc));
#endif
}

struct Bun { uint x, y, z; };

// ---------------------------------------------------------------------------
// counts zeroing (replaces memset) + W1/W2 -> f16 frag-ordered:
// out[((s*NC+c)*64+l)*4+i] = W[s*16+((l>>4)&3)*4+i][c*16+(l&15)]
// ---------------------------------------------------------------------------
__global__ __launch_bounds__(256) void wconv2(const float* __restrict__ W1,
                                              const float* __restrict__ W2,
                                              _Float16* __restrict__ w1h,
                                              _Float16* __restrict__ w2h,
                                              int* __restrict__ counts,
                                              int Ncnt) {
  int idx = blockIdx.x * blockDim.x + threadIdx.x;
  if (idx < Ncnt) counts[idx] = 0;
  const float* W;
  _Float16* outp;
  int NC, NCOLS, base;
  if (idx < 8 * 8 * 256) {  // W1: S=8, NC=8
    W = W1; outp = w1h; NC = 8; NCOLS = 128; base = idx;
  } else if (idx < 8 * 8 * 256 + 8 * 24 * 256) {  // W2: S=8, NC=24
    W = W2; outp = w2h; NC = 24; NCOLS = 384; base = idx - 8 * 8 * 256;
  } else {
    return;
  }
  int i = base & 3;
  int l = (base >> 2) & 63;
  int rem = base >> 8;  // s*NC + c
  int c = rem % NC, s = rem / NC;
  int k = s * 16 + ((l >> 4) & 3) * 4 + i;
  int col = c * 16 + (l & 15);
  outp[base] = (_Float16)W[(size_t)k * NCOLS + col];
}

// ---------------------------------------------------------------------------
// Fused MFMA GEMM + bundle pack:
// bundle[n*128+j] = {(a0,a1),(a2,v0),(v1,v2)} f16, a = silu(ns@W1+b1)@W2+b2.
// ---------------------------------------------------------------------------
__global__ __launch_bounds__(256) void gemm_fused(
    const float* __restrict__ A, const half4* __restrict__ w1h,
    const float* __restrict__ b1, const half4* __restrict__ w2h,
    const float* __restrict__ b2, const float* __restrict__ nvec,
    uint* __restrict__ bundle, int M) {
  __shared__ _Float16 Ah[64][136];
  const int t = threadIdx.x;
  const int w = t >> 6;
  const int l = t & 63;
  const int lr = l & 15, lg = (l >> 4) & 3;
  const int row0 = blockIdx.x * 64;

  for (int i = t; i < 64 * 32; i += 256) {
    int r = i >> 5, c4 = (i & 31) << 2;
    int gr = row0 + r;
    float4 v = make_float4(0.f, 0.f, 0.f, 0.f);
    if (gr < M) v = *(const float4*)&A[(size_t)gr * FDIM + c4];
    half4 hv = {(_Float16)v.x, (_Float16)v.y, (_Float16)v.z, (_Float16)v.w};
    *(half4*)&Ah[r][c4] = hv;
  }
  __syncthreads();

  half4 af[8];
#pragma unroll
  for (int s = 0; s < 8; ++s)
    af[s] = *(const half4*)&Ah[16 * w + lr][s * 16 + lg * 4];

  f32x4 acc1[8];
#pragma unroll
  for (int c = 0; c < 8; ++c) acc1[c] = {0.f, 0.f, 0.f, 0.f};
#pragma unroll
  for (int s = 0; s < 8; ++s) {
#pragma unroll
    for (int c = 0; c < 8; ++c) {
      half4 bf = w1h[(s * 8 + c) * 64 + l];
      acc1[c] = __builtin_amdgcn_mfma_f32_16x16x16f16(af[s], bf, acc1[c], 0, 0, 0);
    }
  }
  __syncthreads();
#pragma unroll
  for (int c = 0; c < 8; ++c) {
    float bb = b1[c * 16 + lr];
#pragma unroll
    for (int r = 0; r < 4; ++r) {
      float x = acc1[c][r] + bb;
      x = x / (1.f + __expf(-x));
      Ah[16 * w + lg * 4 + r][c * 16 + lr] = (_Float16)x;
    }
  }
  __syncthreads();

  half4 hf[8];
#pragma unroll
  for (int s = 0; s < 8; ++s)
    hf[s] = *(const half4*)&Ah[16 * w + lr][s * 16 + lg * 4];

#pragma unroll 1
  for (int cg = 0; cg < 8; ++cg) {
    f32x4 a3[3];
#pragma unroll
    for (int p = 0; p < 3; ++p) a3[p] = {0.f, 0.f, 0.f, 0.f};
#pragma unroll
    for (int s = 0; s < 8; ++s) {
#pragma unroll
      for (int p = 0; p < 3; ++p) {
        half4 bf = w2h[(s * 24 + cg + p * 8) * 64 + l];
        a3[p] = __builtin_amdgcn_mfma_f32_16x16x16f16(hf[s], bf, a3[p], 0, 0, 0);
      }
    }
    const int j = cg * 16 + lr;
    const float bb0 = b2[j], bb1 = b2[j + 128], bb2 = b2[j + 256];
#pragma unroll
    for (int r = 0; r < 4; ++r) {
      int n = row0 + 16 * w + lg * 4 + r;
      if (n >= M) continue;
      const float* vb = nvec + ((size_t)n * FDIM + j) * 3;
      float v0 = vb[0], v1 = vb[1], v2 = vb[2];
      uint* o = bundle + ((size_t)n * FDIM + j) * 3;
      o[0] = packh(a3[0][r] + bb0, a3[1][r] + bb1);
      o[1] = packh(a3[2][r] + bb2, v0);
      o[2] = packh(v1, v2);
    }
  }
}

// ---------------------------------------------------------------------------
// CSR build
// ---------------------------------------------------------------------------
__global__ __launch_bounds__(256) void hist_kernel(const float* __restrict__ adj,
                                                   int* __restrict__ counts,
                                                   int E) {
  int e = blockIdx.x * blockDim.x + threadIdx.x;
  if (e < E) atomicAdd(&counts[(int)adj[(size_t)e * 6]], 1);
}

__global__ __launch_bounds__(1024) void scan_kernel(
    const int* __restrict__ counts, int* __restrict__ offs,
    int* __restrict__ cursor, int n) {
  __shared__ int part[1024];
  const int tid = threadIdx.x;
  const int CH = (n + 1023) >> 10;
  const int b = tid * CH;
  const int e = min(b + CH, n);
  int s = 0;
  for (int i = b; i < e; ++i) s += counts[i];
  part[tid] = s;
  __syncthreads();
  for (int off = 1; off < 1024; off <<= 1) {
    int v = (tid >= off) ? part[tid - off] : 0;
    __syncthreads();
    part[tid] += v;
    __syncthreads();
  }
  int run = part[tid] - s;
  if (tid == 0) offs[0] = 0;
  for (int i = b; i < e; ++i) {
    int c = counts[i];
    cursor[i] = run;
    run += c;
    offs[i + 1] = run;
  }
}

// ---------------------------------------------------------------------------
// Edge prep: record stored at CSR SLOT p -> per-node payloads contiguous.
// 56B record (stride 14 u32):
// w0=src, w1=(rhx,rhy), w2=(rhz,cut), w3..12=(c0..c19), c_n=sin(nx)*invd*cut
// ---------------------------------------------------------------------------
__global__ __launch_bounds__(256) void edge_prep(const float* __restrict__ adj,
                                                 int* __restrict__ cursor,
                                                 int* __restrict__ eids,
                                                 uint* __restrict__ rec, int E) {
  int e = blockIdx.x * blockDim.x + threadIdx.x;
  if (e >= E) return;
  const float* a = adj + (size_t)e * 6;
  int dst = (int)a[0];
  int src = (int)a[1];
  float rx = a[2], ry = a[3], rz = a[4], d = a[5];

  int p = atomicAdd(&cursor[dst], 1);
  eids[p] = e;

  float x = d * (PI_F / CUTOFF_F);
  float sx, cx;
  __sincosf(x, &sx, &cx);
  float invd = 1.f / d;
  float cut = (d < CUTOFF_F) ? 0.5f * (cx + 1.f) : 0.f;
  float sc = invd * cut;

  union { uint w[14]; uint2 q[7]; } R;
  R.w[0] = (uint)src;
  R.w[1] = packh(rx * invd, ry * invd);
  R.w[2] = packh(rz * invd, cut);
  float twoc = 2.f * cx;
  float sprev = 0.f, scur = sx;
  float c[NRBF];
#pragma unroll
  for (int n = 0; n < NRBF; ++n) {
    c[n] = scur * sc;
    float nxt = fmaf(twoc, scur, -sprev);
    sprev = scur;
    scur = nxt;
  }
#pragma unroll
  for (int m = 0; m < 10; ++m) R.w[3 + m] = packh(c[2 * m], c[2 * m + 1]);
  R.w[13] = 0;
  uint2* o = (uint2*)(rec + (size_t)p * 14);
#pragma unroll
  for (int m = 0; m < 7; ++m) o[m] = R.q[m];
}

// ---------------------------------------------------------------------------
// Persistent per-dst accumulation. Bundle prefetch depth-3 via sh_src (LDS),
// decoupled from the rec scalar chain.
// ---------------------------------------------------------------------------
__global__ __launch_bounds__(128) void accum_kernel(
    const uint* __restrict__ rec, const uint* __restrict__ bundle,
    const float* __restrict__ nvec, const float* __restrict__ Wr,
    const float* __restrict__ br, const float* __restrict__ ns,
    const int* __restrict__ offs, const int* __restrict__ eids,
    float* __restrict__ out_s, float* __restrict__ out_v, int Nn) {
  const int j = threadIdx.x;

  h2 wp0[10], wp1[10], wp2[10];
#pragma unroll
  for (int m = 0; m < 10; ++m) {
    wp0[m] = h2{(_Float16)Wr[(2 * m) * 384 + j], (_Float16)Wr[(2 * m + 1) * 384 + j]};
    wp1[m] = h2{(_Float16)Wr[(2 * m) * 384 + 128 + j], (_Float16)Wr[(2 * m + 1) * 384 + 128 + j]};
    wp2[m] = h2{(_Float16)Wr[(2 * m) * 384 + 256 + j], (_Float16)Wr[(2 * m + 1) * 384 + 256 + j]};
  }
  const float brj0 = br[j], brj1 = br[j + 128], brj2 = br[j + 256];

  __shared__ int sh_e[128], sh_pos[128], sh_src[128];

#define LOADREC(R, t)                                                      \
  {                                                                        \
    int su = __builtin_amdgcn_readfirstlane(beg + sh_pos[(t)]);            \
    const uint* p = rec + (size_t)(uint)su * 14;                           \
    _Pragma("unroll") for (int w_ = 0; w_ < 13; ++w_) R[w_] = p[w_];       \
  }
#define LOADB(B, tt)                                                       \
  {                                                                        \
    int su = __builtin_amdgcn_readfirstlane(sh_src[(tt)]);                 \
    const uint* p = bundle + ((size_t)(uint)su * FDIM + j) * 3;            \
    (B).x = p[0];                                                          \
    (B).y = p[1];                                                          \
    (B).z = p[2];                                                          \
  }
#define COMPUTE(RC, BB)                                                    \
  {                                                                        \
    float rhx = h_lo(RC[1]), rhy = h_hi(RC[1]);                            \
    float rhz = h_lo(RC[2]), cut = h_hi(RC[2]);                            \
    float w0 = cut * brj0, w1 = cut * brj1, w2 = cut * brj2;               \
    _Pragma("unroll") for (int q = 0; q < 10; ++q) {                       \
      w0 = dot2(RC[3 + q], wp0[q], w0);                                    \
      w1 = dot2(RC[3 + q], wp1[q], w1);                                    \
      w2 = dot2(RC[3 + q], wp2[q], w2);                                    \
    }                                                                      \
    float s1 = h_lo((BB).x) * w0;                                          \
    float s2 = h_hi((BB).x) * w1;                                          \
    float s3 = h_lo((BB).y) * w2;                                          \
    float pv0 = h_hi((BB).y), pv1 = h_lo((BB).z), pv2 = h_hi((BB).z);      \
    acc_s += s2;                                                           \
    av0 = fmaf(pv0, s1, fmaf(s3, rhx, av0));                               \
    av1 = fmaf(pv1, s1, fmaf(s3, rhy, av1));                               \
    av2 = fmaf(pv2, s1, fmaf(s3, rhz, av2));                               \
  }

  for (int d = blockIdx.x; d < Nn; d += gridDim.x) {
    const int beg = offs[d];
    const int cnt = offs[d + 1] - beg;
    const int m = cnt < 128 ? cnt : 128;
    if (j < m) sh_e[j] = eids[beg + j];
    __syncthreads();
    if (j < m) {  // rank sort by eid (unique); also stage src per rank
      int v = sh_e[j];
      int r = 0;
      for (int u = 0; u < m; ++u) r += (sh_e[u] < v);
      sh_pos[r] = j;
      sh_src[r] = (int)rec[(size_t)(uint)(beg + j) * 14];
    }
    __syncthreads();

    float acc_s = 0.f, av0 = 0.f, av1 = 0.f, av2 = 0.f;

    uint r_cur[13], r_nxt[13];
    Bun b0_ = {}, b1_ = {}, b2_ = {}, b3_ = {};
    if (m > 0) { LOADB(b0_, 0); LOADREC(r_cur, 0); }
    if (m > 1) { LOADB(b1_, 1); LOADREC(r_nxt, 1); }
    if (m > 2) LOADB(b2_, 2);

    for (int t = 0; t < m; ++t) {
      if (t + 3 < m) LOADB(b3_, t + 3);
      uint r_n2[13];
      if (t + 2 < m) LOADREC(r_n2, t + 2);

      COMPUTE(r_cur, b0_);

#pragma unroll
      for (int w_ = 0; w_ < 13; ++w_) {
        r_cur[w_] = r_nxt[w_];
        r_nxt[w_] = r_n2[w_];
      }
      b0_ = b1_;
      b1_ = b2_;
      b2_ = b3_;
    }

    // slow tail (cnt > 128 — statistically never at E/N = 16)
    for (int t = 128; t < cnt; ++t) {
      uint R[13];
      {
        int su = __builtin_amdgcn_readfirstlane(beg + t);
        const uint* p = rec + (size_t)(uint)su * 14;
#pragma unroll
        for (int w_ = 0; w_ < 13; ++w_) R[w_] = p[w_];
      }
      Bun Bx;
      {
        const uint* p = bundle + ((size_t)(uint)R[0] * FDIM + j) * 3;
        Bx.x = p[0];
        Bx.y = p[1];
        Bx.z = p[2];
      }
      COMPUTE(R, Bx);
    }

    out_s[(size_t)d * FDIM + j] = ns[(size_t)d * FDIM + j] + acc_s;
    float* vo = out_v + (size_t)d * 384 + j * 3;
    const float* vi = nvec + (size_t)d * 384 + j * 3;
    vo[0] = vi[0] + av0;
    vo[1] = vi[1] + av1;
    vo[2] = vi[2] + av2;
  }
#undef LOADREC
#undef LOADB
#undef COMPUTE
}

// ---------------------------------------------------------------------------
extern "C" void kernel_launch(void* const* d_in, const int* in_sizes, int n_in,
                              void* d_out, int out_size, void* d_ws,
                              size_t ws_size, hipStream_t stream) {
  const float* node_scalar = (const float*)d_in[0];
  const float* node_vector = (const float*)d_in[1];
  const float* adj = (const float*)d_in[2];
  const float* W1 = (const float*)d_in[3];
  const float* b1 = (const float*)d_in[4];
  const float* W2 = (const float*)d_in[5];
  const float* b2 = (const float*)d_in[6];
  const float* Wr = (const float*)d_in[7];
  const float* br = (const float*)d_in[8];

  const int N = in_sizes[0] / FDIM;
  const int E = in_sizes[2] / 6;

  float* out = (float*)d_out;
  float* out_s = out;
  float* out_v = out + (size_t)N * FDIM;

  // workspace: bundle | rec(56B/edge, CSR order) | w1h | w2h | counts | offs | cursor | eids
  char* w = (char*)d_ws;
  uint* bundle = (uint*)w;
  size_t off = (size_t)N * FDIM * 12;
  uint* rec = (uint*)(w + off);
  off += (size_t)E * 56;
  _Float16* w1h = (_Float16*)(w + off);
  off += 8 * 8 * 256 * 2;
  _Float16* w2h = (_Float16*)(w + off);
  off += 8 * 24 * 256 * 2;
  int* counts = (int*)(w + off);
  int* offs = counts + N;
  int* cursor = offs + N + 1;
  int* eids = cursor + N;

  // wconv2 also zeroes counts (must precede hist)
  wconv2<<<(8 * 8 * 256 + 8 * 24 * 256 + 255) / 256, 256, 0, stream>>>(
      W1, W2, w1h, w2h, counts, N);
  hist_kernel<<<(E + 255) / 256, 256, 0, stream>>>(adj, counts, E);
  scan_kernel<<<1, 1024, 0, stream>>>(counts, offs, cursor, N);
  edge_prep<<<(E + 255) / 256, 256, 0, stream>>>(adj, cursor, eids, rec, E);

  gemm_fused<<<(N + 63) / 64, 256, 0, stream>>>(node_scalar, (const half4*)w1h,
                                                b1, (const half4*)w2h, b2,
                                                node_vector, bundle, N);

  const int agrid = N < 4096 ? N : 4096;
  accum_kernel<<<agrid, 128, 0, stream>>>(rec, bundle, node_vector, Wr, br,
                                          node_scalar, offs, eids, out_s,
                                          out_v, N);
}

// Round 12
// 303.185 us; speedup vs baseline: 1.0567x; 1.0567x over previous
//
#include <hip/hip_runtime.h>

#define FDIM 128
#define NRBF 20
constexpr float CUTOFF_F = 5.0f;
constexpr float PI_F = 3.14159265358979323846f;

typedef _Float16 h2 __attribute__((ext_vector_type(2)));
typedef _Float16 half4 __attribute__((ext_vector_type(4)));
typedef float f32x4 __attribute__((ext_vector_type(4)));

__device__ __forceinline__ uint packh(float a, float b) {
  union { _Float16 h[2]; uint u; } x;
  x.h[0] = (_Float16)a;
  x.h[1] = (_Float16)b;
  return x.u;
}
__device__ __forceinline__ float h_lo(uint w) {
  union { uint u; _Float16 h[2]; } x;
  x.u = w;
  return (float)x.h[0];
}
__device__ __forceinline__ float h_hi(uint w) {
  union { uint u; _Float16 h[2]; } x;
  x.u = w;
  return (float)x.h[1];
}
__device__ __forceinline__ float dot2(uint cw, h2 w, float acc) {
#if __has_builtin(__builtin_amdgcn_fdot2)
  h2 c = __builtin_bit_cast(h2, cw);
  return __builtin_amdgcn_fdot2(c, w, acc, false);
#else
  return fmaf(h_hi(cw), (float)w[1], fmaf(h_lo(cw), (float)w[0], acc));
#endif
}

struct Bun { uint x, y, z; };

// ---------------------------------------------------------------------------
// counts zeroing (replaces memset) + W1/W2 -> f16 frag-ordered:
// out[((s*NC+c)*64+l)*4+i] = W[s*16+((l>>4)&3)*4+i][c*16+(l&15)]
// ---------------------------------------------------------------------------
__global__ __launch_bounds__(256) void wconv2(const float* __restrict__ W1,
                                              const float* __restrict__ W2,
                                              _Float16* __restrict__ w1h,
                                              _Float16* __restrict__ w2h,
                                              int* __restrict__ counts,
                                              int Ncnt) {
  int idx = blockIdx.x * blockDim.x + threadIdx.x;
  if (idx < Ncnt) counts[idx] = 0;
  const float* W;
  _Float16* outp;
  int NC, NCOLS, base;
  if (idx < 8 * 8 * 256) {  // W1: S=8, NC=8
    W = W1; outp = w1h; NC = 8; NCOLS = 128; base = idx;
  } else if (idx < 8 * 8 * 256 + 8 * 24 * 256) {  // W2: S=8, NC=24
    W = W2; outp = w2h; NC = 24; NCOLS = 384; base = idx - 8 * 8 * 256;
  } else {
    return;
  }
  int i = base & 3;
  int l = (base >> 2) & 63;
  int rem = base >> 8;  // s*NC + c
  int c = rem % NC, s = rem / NC;
  int k = s * 16 + ((l >> 4) & 3) * 4 + i;
  int col = c * 16 + (l & 15);
  outp[base] = (_Float16)W[(size_t)k * NCOLS + col];
}

// ---------------------------------------------------------------------------
// CSR build
// ---------------------------------------------------------------------------
__global__ __launch_bounds__(256) void hist_kernel(const float* __restrict__ adj,
                                                   int* __restrict__ counts,
                                                   int E) {
  int e = blockIdx.x * blockDim.x + threadIdx.x;
  if (e < E) atomicAdd(&counts[(int)adj[(size_t)e * 6]], 1);
}

__global__ __launch_bounds__(1024) void scan_kernel(
    const int* __restrict__ counts, int* __restrict__ offs,
    int* __restrict__ cursor, int n) {
  __shared__ int part[1024];
  const int tid = threadIdx.x;
  const int CH = (n + 1023) >> 10;
  const int b = tid * CH;
  const int e = min(b + CH, n);
  int s = 0;
  for (int i = b; i < e; ++i) s += counts[i];
  part[tid] = s;
  __syncthreads();
  for (int off = 1; off < 1024; off <<= 1) {
    int v = (tid >= off) ? part[tid - off] : 0;
    __syncthreads();
    part[tid] += v;
    __syncthreads();
  }
  int run = part[tid] - s;
  if (tid == 0) offs[0] = 0;
  for (int i = b; i < e; ++i) {
    int c = counts[i];
    cursor[i] = run;
    run += c;
    offs[i + 1] = run;
  }
}

// ---------------------------------------------------------------------------
// Fused: blocks [0,GB) = MFMA GEMM + bundle pack; blocks [GB,..) = edge_prep.
// gemm: bundle[n*128+j] = {(a0,a1),(a2,v0),(v1,v2)} f16, a=silu(ns@W1+b1)@W2+b2
// edge: rec at CSR slot p (contiguous per node), 56B record:
//   w0=src, w1=(rhx,rhy), w2=(rhz,cut), w3..12=(c0..c19), c_n=sin(nx)*invd*cut
// ---------------------------------------------------------------------------
__global__ __launch_bounds__(256) void prep_gemm(
    const float* __restrict__ A, const half4* __restrict__ w1h,
    const float* __restrict__ b1, const half4* __restrict__ w2h,
    const float* __restrict__ b2, const float* __restrict__ nvec,
    uint* __restrict__ bundle, int M, const float* __restrict__ adj,
    int* __restrict__ cursor, int* __restrict__ eids, uint* __restrict__ rec,
    int E, int GB) {
  __shared__ _Float16 Ah[64][136];
  const int t = threadIdx.x;

  if ((int)blockIdx.x >= GB) {
    // ----- edge_prep branch -----
    int e = ((int)blockIdx.x - GB) * 256 + t;
    if (e >= E) return;
    const float* a = adj + (size_t)e * 6;
    int dst = (int)a[0];
    int src = (int)a[1];
    float rx = a[2], ry = a[3], rz = a[4], d = a[5];

    int p = atomicAdd(&cursor[dst], 1);
    eids[p] = e;

    float x = d * (PI_F / CUTOFF_F);
    float sx, cx;
    __sincosf(x, &sx, &cx);
    float invd = 1.f / d;
    float cut = (d < CUTOFF_F) ? 0.5f * (cx + 1.f) : 0.f;
    float sc = invd * cut;

    union { uint w[14]; uint2 q[7]; } R;
    R.w[0] = (uint)src;
    R.w[1] = packh(rx * invd, ry * invd);
    R.w[2] = packh(rz * invd, cut);
    float twoc = 2.f * cx;
    float sprev = 0.f, scur = sx;
    float c[NRBF];
#pragma unroll
    for (int n = 0; n < NRBF; ++n) {
      c[n] = scur * sc;
      float nxt = fmaf(twoc, scur, -sprev);
      sprev = scur;
      scur = nxt;
    }
#pragma unroll
    for (int m = 0; m < 10; ++m) R.w[3 + m] = packh(c[2 * m], c[2 * m + 1]);
    R.w[13] = 0;
    uint2* o = (uint2*)(rec + (size_t)p * 14);
#pragma unroll
    for (int m = 0; m < 7; ++m) o[m] = R.q[m];
    return;
  }

  // ----- gemm branch -----
  const int w = t >> 6;
  const int l = t & 63;
  const int lr = l & 15, lg = (l >> 4) & 3;
  const int row0 = blockIdx.x * 64;

  for (int i = t; i < 64 * 32; i += 256) {
    int r = i >> 5, c4 = (i & 31) << 2;
    int gr = row0 + r;
    float4 v = make_float4(0.f, 0.f, 0.f, 0.f);
    if (gr < M) v = *(const float4*)&A[(size_t)gr * FDIM + c4];
    half4 hv = {(_Float16)v.x, (_Float16)v.y, (_Float16)v.z, (_Float16)v.w};
    *(half4*)&Ah[r][c4] = hv;
  }
  __syncthreads();

  half4 af[8];
#pragma unroll
  for (int s = 0; s < 8; ++s)
    af[s] = *(const half4*)&Ah[16 * w + lr][s * 16 + lg * 4];

  f32x4 acc1[8];
#pragma unroll
  for (int c = 0; c < 8; ++c) acc1[c] = {0.f, 0.f, 0.f, 0.f};
#pragma unroll
  for (int s = 0; s < 8; ++s) {
#pragma unroll
    for (int c = 0; c < 8; ++c) {
      half4 bf = w1h[(s * 8 + c) * 64 + l];
      acc1[c] = __builtin_amdgcn_mfma_f32_16x16x16f16(af[s], bf, acc1[c], 0, 0, 0);
    }
  }
  __syncthreads();
#pragma unroll
  for (int c = 0; c < 8; ++c) {
    float bb = b1[c * 16 + lr];
#pragma unroll
    for (int r = 0; r < 4; ++r) {
      float x = acc1[c][r] + bb;
      x = x / (1.f + __expf(-x));
      Ah[16 * w + lg * 4 + r][c * 16 + lr] = (_Float16)x;
    }
  }
  __syncthreads();

  half4 hf[8];
#pragma unroll
  for (int s = 0; s < 8; ++s)
    hf[s] = *(const half4*)&Ah[16 * w + lr][s * 16 + lg * 4];

#pragma unroll 1
  for (int cg = 0; cg < 8; ++cg) {
    f32x4 a3[3];
#pragma unroll
    for (int p = 0; p < 3; ++p) a3[p] = {0.f, 0.f, 0.f, 0.f};
#pragma unroll
    for (int s = 0; s < 8; ++s) {
#pragma unroll
      for (int p = 0; p < 3; ++p) {
        half4 bf = w2h[(s * 24 + cg + p * 8) * 64 + l];
        a3[p] = __builtin_amdgcn_mfma_f32_16x16x16f16(hf[s], bf, a3[p], 0, 0, 0);
      }
    }
    const int j = cg * 16 + lr;
    const float bb0 = b2[j], bb1 = b2[j + 128], bb2 = b2[j + 256];
#pragma unroll
    for (int r = 0; r < 4; ++r) {
      int n = row0 + 16 * w + lg * 4 + r;
      if (n >= M) continue;
      const float* vb = nvec + ((size_t)n * FDIM + j) * 3;
      float v0 = vb[0], v1 = vb[1], v2 = vb[2];
      uint* o = bundle + ((size_t)n * FDIM + j) * 3;
      o[0] = packh(a3[0][r] + bb0, a3[1][r] + bb1);
      o[1] = packh(a3[2][r] + bb2, v0);
      o[2] = packh(v1, v2);
    }
  }
}

// ---------------------------------------------------------------------------
// Persistent per-dst accumulation (R10 structure; unroll-3 static rotation
// removes the 29 shift-movs/edge while keeping R10's exact load depths).
// ---------------------------------------------------------------------------
__global__ __launch_bounds__(128) void accum_kernel(
    const uint* __restrict__ rec, const uint* __restrict__ bundle,
    const float* __restrict__ nvec, const float* __restrict__ Wr,
    const float* __restrict__ br, const float* __restrict__ ns,
    const int* __restrict__ offs, const int* __restrict__ eids,
    float* __restrict__ out_s, float* __restrict__ out_v, int Nn) {
  const int j = threadIdx.x;

  h2 wp0[10], wp1[10], wp2[10];
#pragma unroll
  for (int m = 0; m < 10; ++m) {
    wp0[m] = h2{(_Float16)Wr[(2 * m) * 384 + j], (_Float16)Wr[(2 * m + 1) * 384 + j]};
    wp1[m] = h2{(_Float16)Wr[(2 * m) * 384 + 128 + j], (_Float16)Wr[(2 * m + 1) * 384 + 128 + j]};
    wp2[m] = h2{(_Float16)Wr[(2 * m) * 384 + 256 + j], (_Float16)Wr[(2 * m + 1) * 384 + 256 + j]};
  }
  const float brj0 = br[j], brj1 = br[j + 128], brj2 = br[j + 256];

  __shared__ int sh_e[128], sh_pos[128];

#define SLOT(t) ((t) < 128 ? sh_pos[(t)] : (t))
#define LOADREC(R, t)                                                      \
  {                                                                        \
    int su = __builtin_amdgcn_readfirstlane(beg + SLOT(t));                \
    const uint* p = rec + (size_t)(uint)su * 14;                           \
    _Pragma("unroll") for (int w_ = 0; w_ < 13; ++w_) R[w_] = p[w_];       \
  }
#define LOADB(B, SRC)                                                      \
  {                                                                        \
    const uint* p = bundle + ((size_t)(uint)(SRC)*FDIM + j) * 3;           \
    (B).x = p[0];                                                          \
    (B).y = p[1];                                                          \
    (B).z = p[2];                                                          \
  }
#define COMPUTE(RC, BB)                                                    \
  {                                                                        \
    float rhx = h_lo(RC[1]), rhy = h_hi(RC[1]);                            \
    float rhz = h_lo(RC[2]), cut = h_hi(RC[2]);                            \
    float w0 = cut * brj0, w1 = cut * brj1, w2 = cut * brj2;               \
    _Pragma("unroll") for (int q = 0; q < 10; ++q) {                       \
      w0 = dot2(RC[3 + q], wp0[q], w0);                                    \
      w1 = dot2(RC[3 + q], wp1[q], w1);                                    \
      w2 = dot2(RC[3 + q], wp2[q], w2);                                    \
    }                                                                      \
    float s1 = h_lo((BB).x) * w0;                                          \
    float s2 = h_hi((BB).x) * w1;                                          \
    float s3 = h_lo((BB).y) * w2;                                          \
    float pv0 = h_hi((BB).y), pv1 = h_lo((BB).z), pv2 = h_hi((BB).z);      \
    acc_s += s2;                                                           \
    av0 = fmaf(pv0, s1, fmaf(s3, rhx, av0));                               \
    av1 = fmaf(pv1, s1, fmaf(s3, rhy, av1));                               \
    av2 = fmaf(pv2, s1, fmaf(s3, rhz, av2));                               \
  }

  for (int d = blockIdx.x; d < Nn; d += gridDim.x) {
    const int beg = offs[d];
    const int cnt = offs[d + 1] - beg;
    const int m = cnt < 128 ? cnt : 128;
    if (j < m) sh_e[j] = eids[beg + j];
    __syncthreads();
    if (j < m) {  // rank sort by eid (unique) -> slot index of t-th smallest
      int v = sh_e[j];
      int r = 0;
      for (int u = 0; u < m; ++u) r += (sh_e[u] < v);
      sh_pos[r] = j;
    }
    __syncthreads();

    float acc_s = 0.f, av0 = 0.f, av1 = 0.f, av2 = 0.f;

    uint r0[13], r1[13], r2[13];
    Bun b0_ = {}, b1_ = {}, b2_ = {};
    if (m > 0) LOADREC(r0, 0);
    if (m > 1) LOADREC(r1, 1);
    if (m > 0) LOADB(b0_, r0[0]);
    if (m > 1) LOADB(b1_, r1[0]);

    for (int t = 0; t < m; t += 3) {
      // pos0: edge t (r0/b0_); rec t+2 -> r2; after compute, bundle t+2
      if (t + 2 < m) LOADREC(r2, t + 2);
      COMPUTE(r0, b0_);
      if (t + 2 < m) LOADB(b2_, r2[0]);
      // pos1: edge t+1 (r1/b1_)
      if (t + 1 >= m) break;
      if (t + 3 < m) LOADREC(r0, t + 3);
      COMPUTE(r1, b1_);
      if (t + 3 < m) LOADB(b0_, r0[0]);
      // pos2: edge t+2 (r2/b2_)
      if (t + 2 >= m) break;
      if (t + 4 < m) LOADREC(r1, t + 4);
      COMPUTE(r2, b2_);
      if (t + 4 < m) LOADB(b1_, r1[0]);
    }

    // slow tail (cnt > 128 — statistically never at E/N = 16)
    for (int t = 128; t < cnt; ++t) {
      uint R[13];
      {
        int su = __builtin_amdgcn_readfirstlane(beg + t);
        const uint* p = rec + (size_t)(uint)su * 14;
#pragma unroll
        for (int w_ = 0; w_ < 13; ++w_) R[w_] = p[w_];
      }
      Bun Bx;
      LOADB(Bx, R[0]);
      COMPUTE(R, Bx);
    }

    out_s[(size_t)d * FDIM + j] = ns[(size_t)d * FDIM + j] + acc_s;
    float* vo = out_v + (size_t)d * 384 + j * 3;
    const float* vi = nvec + (size_t)d * 384 + j * 3;
    vo[0] = vi[0] + av0;
    vo[1] = vi[1] + av1;
    vo[2] = vi[2] + av2;
  }
#undef SLOT
#undef LOADREC
#undef LOADB
#undef COMPUTE
}

// ---------------------------------------------------------------------------
extern "C" void kernel_launch(void* const* d_in, const int* in_sizes, int n_in,
                              void* d_out, int out_size, void* d_ws,
                              size_t ws_size, hipStream_t stream) {
  const float* node_scalar = (const float*)d_in[0];
  const float* node_vector = (const float*)d_in[1];
  const float* adj = (const float*)d_in[2];
  const float* W1 = (const float*)d_in[3];
  const float* b1 = (const float*)d_in[4];
  const float* W2 = (const float*)d_in[5];
  const float* b2 = (const float*)d_in[6];
  const float* Wr = (const float*)d_in[7];
  const float* br = (const float*)d_in[8];

  const int N = in_sizes[0] / FDIM;
  const int E = in_sizes[2] / 6;

  float* out = (float*)d_out;
  float* out_s = out;
  float* out_v = out + (size_t)N * FDIM;

  // workspace: bundle | rec(56B/edge, CSR order) | w1h | w2h | counts | offs | cursor | eids
  char* w = (char*)d_ws;
  uint* bundle = (uint*)w;
  size_t off = (size_t)N * FDIM * 12;
  uint* rec = (uint*)(w + off);
  off += (size_t)E * 56;
  _Float16* w1h = (_Float16*)(w + off);
  off += 8 * 8 * 256 * 2;
  _Float16* w2h = (_Float16*)(w + off);
  off += 8 * 24 * 256 * 2;
  int* counts = (int*)(w + off);
  int* offs = counts + N;
  int* cursor = offs + N + 1;
  int* eids = cursor + N;

  // wconv2 also zeroes counts (separate dispatch precedes hist's atomics)
  wconv2<<<(8 * 8 * 256 + 8 * 24 * 256 + 255) / 256, 256, 0, stream>>>(
      W1, W2, w1h, w2h, counts, N);
  hist_kernel<<<(E + 255) / 256, 256, 0, stream>>>(adj, counts, E);
  scan_kernel<<<1, 1024, 0, stream>>>(counts, offs, cursor, N);

  const int GB = (N + 63) / 64;
  const int EB = (E + 255) / 256;
  prep_gemm<<<GB + EB, 256, 0, stream>>>(node_scalar, (const half4*)w1h, b1,
                                         (const half4*)w2h, b2, node_vector,
                                         bundle, N, adj, cursor, eids, rec, E,
                                         GB);

  const int agrid = N < 4096 ? N : 4096;
  accum_kernel<<<agrid, 128, 0, stream>>>(rec, bundle, node_vector, Wr, br,
                                          node_scalar, offs, eids, out_s,
                                          out_v, N);
}

// Round 13
// 273.427 us; speedup vs baseline: 1.1717x; 1.1088x over previous
//
#include <hip/hip_runtime.h>

#define FDIM 128
#define NRBF 20
constexpr float CUTOFF_F = 5.0f;
constexpr float PI_F = 3.14159265358979323846f;

typedef _Float16 h2 __attribute__((ext_vector_type(2)));
typedef _Float16 half4 __attribute__((ext_vector_type(4)));
typedef float f32x4 __attribute__((ext_vector_type(4)));

__device__ __forceinline__ uint packh(float a, float b) {
  union { _Float16 h[2]; uint u; } x;
  x.h[0] = (_Float16)a;
  x.h[1] = (_Float16)b;
  return x.u;
}
__device__ __forceinline__ float h_lo(uint w) {
  union { uint u; _Float16 h[2]; } x;
  x.u = w;
  return (float)x.h[0];
}
__device__ __forceinline__ float h_hi(uint w) {
  union { uint u; _Float16 h[2]; } x;
  x.u = w;
  return (float)x.h[1];
}
__device__ __forceinline__ float dot2(uint cw, h2 w, float acc) {
#if __has_builtin(__builtin_amdgcn_fdot2)
  h2 c = __builtin_bit_cast(h2, cw);
  return __builtin_amdgcn_fdot2(c, w, acc, false);
#else
  return fmaf(h_hi(cw), (float)w[1], fmaf(h_lo(cw), (float)w[0], acc));
#endif
}

// ---------------------------------------------------------------------------
// counts zeroing (replaces memset) + W1/W2 -> f16 frag-ordered:
// out[((s*NC+c)*64+l)*4+i] = W[s*16+((l>>4)&3)*4+i][c*16+(l&15)]
// ---------------------------------------------------------------------------
__global__ __launch_bounds__(256) void wconv2(const float* __restrict__ W1,
                                              const float* __restrict__ W2,
                                              _Float16* __restrict__ w1h,
                                              _Float16* __restrict__ w2h,
                                              int* __restrict__ counts,
                                              int Ncnt) {
  int idx = blockIdx.x * blockDim.x + threadIdx.x;
  if (idx < Ncnt) counts[idx] = 0;
  const float* W;
  _Float16* outp;
  int NC, NCOLS, base;
  if (idx < 8 * 8 * 256) {  // W1: S=8, NC=8
    W = W1; outp = w1h; NC = 8; NCOLS = 128; base = idx;
  } else if (idx < 8 * 8 * 256 + 8 * 24 * 256) {  // W2: S=8, NC=24
    W = W2; outp = w2h; NC = 24; NCOLS = 384; base = idx - 8 * 8 * 256;
  } else {
    return;
  }
  int i = base & 3;
  int l = (base >> 2) & 63;
  int rem = base >> 8;  // s*NC + c
  int c = rem % NC, s = rem / NC;
  int k = s * 16 + ((l >> 4) & 3) * 4 + i;
  int col = c * 16 + (l & 15);
  outp[base] = (_Float16)W[(size_t)k * NCOLS + col];
}

// ---------------------------------------------------------------------------
// CSR build
// ---------------------------------------------------------------------------
__global__ __launch_bounds__(256) void hist_kernel(const float* __restrict__ adj,
                                                   int* __restrict__ counts,
                                                   int E) {
  int e = blockIdx.x * blockDim.x + threadIdx.x;
  if (e < E) atomicAdd(&counts[(int)adj[(size_t)e * 6]], 1);
}

__global__ __launch_bounds__(1024) void scan_kernel(
    const int* __restrict__ counts, int* __restrict__ offs,
    int* __restrict__ cursor, int n) {
  __shared__ int part[1024];
  const int tid = threadIdx.x;
  const int CH = (n + 1023) >> 10;
  const int b = tid * CH;
  const int e = min(b + CH, n);
  int s = 0;
  for (int i = b; i < e; ++i) s += counts[i];
  part[tid] = s;
  __syncthreads();
  for (int off = 1; off < 1024; off <<= 1) {
    int v = (tid >= off) ? part[tid - off] : 0;
    __syncthreads();
    part[tid] += v;
    __syncthreads();
  }
  int run = part[tid] - s;
  if (tid == 0) offs[0] = 0;
  for (int i = b; i < e; ++i) {
    int c = counts[i];
    cursor[i] = run;
    run += c;
    offs[i + 1] = run;
  }
}

// ---------------------------------------------------------------------------
// Fused: blocks [0,GB) = MFMA GEMM + bundle pack; blocks [GB,..) = edge_prep.
// gemm: bundle[n*128+j] = {(a0,a1),(a2,v0),(v1,v2)} f16, a=silu(ns@W1+b1)@W2+b2
// edge: rec at CSR slot p (contiguous per node), 56B record:
//   w0=src, w1=(rhx,rhy), w2=(rhz,cut), w3..12=(c0..c19), c_n=sin(nx)*invd*cut
// ---------------------------------------------------------------------------
__global__ __launch_bounds__(256) void prep_gemm(
    const float* __restrict__ A, const half4* __restrict__ w1h,
    const float* __restrict__ b1, const half4* __restrict__ w2h,
    const float* __restrict__ b2, const float* __restrict__ nvec,
    uint* __restrict__ bundle, int M, const float* __restrict__ adj,
    int* __restrict__ cursor, int* __restrict__ eids, uint* __restrict__ rec,
    int E, int GB) {
  __shared__ _Float16 Ah[64][136];
  const int t = threadIdx.x;

  if ((int)blockIdx.x >= GB) {
    // ----- edge_prep branch -----
    int e = ((int)blockIdx.x - GB) * 256 + t;
    if (e >= E) return;
    const float* a = adj + (size_t)e * 6;
    int dst = (int)a[0];
    int src = (int)a[1];
    float rx = a[2], ry = a[3], rz = a[4], d = a[5];

    int p = atomicAdd(&cursor[dst], 1);
    eids[p] = e;

    float x = d * (PI_F / CUTOFF_F);
    float sx, cx;
    __sincosf(x, &sx, &cx);
    float invd = 1.f / d;
    float cut = (d < CUTOFF_F) ? 0.5f * (cx + 1.f) : 0.f;
    float sc = invd * cut;

    union { uint w[14]; uint2 q[7]; } R;
    R.w[0] = (uint)src;
    R.w[1] = packh(rx * invd, ry * invd);
    R.w[2] = packh(rz * invd, cut);
    float twoc = 2.f * cx;
    float sprev = 0.f, scur = sx;
    float c[NRBF];
#pragma unroll
    for (int n = 0; n < NRBF; ++n) {
      c[n] = scur * sc;
      float nxt = fmaf(twoc, scur, -sprev);
      sprev = scur;
      scur = nxt;
    }
#pragma unroll
    for (int m = 0; m < 10; ++m) R.w[3 + m] = packh(c[2 * m], c[2 * m + 1]);
    R.w[13] = 0;
    uint2* o = (uint2*)(rec + (size_t)p * 14);
#pragma unroll
    for (int m = 0; m < 7; ++m) o[m] = R.q[m];
    return;
  }

  // ----- gemm branch -----
  const int w = t >> 6;
  const int l = t & 63;
  const int lr = l & 15, lg = (l >> 4) & 3;
  const int row0 = blockIdx.x * 64;

  for (int i = t; i < 64 * 32; i += 256) {
    int r = i >> 5, c4 = (i & 31) << 2;
    int gr = row0 + r;
    float4 v = make_float4(0.f, 0.f, 0.f, 0.f);
    if (gr < M) v = *(const float4*)&A[(size_t)gr * FDIM + c4];
    half4 hv = {(_Float16)v.x, (_Float16)v.y, (_Float16)v.z, (_Float16)v.w};
    *(half4*)&Ah[r][c4] = hv;
  }
  __syncthreads();

  half4 af[8];
#pragma unroll
  for (int s = 0; s < 8; ++s)
    af[s] = *(const half4*)&Ah[16 * w + lr][s * 16 + lg * 4];

  f32x4 acc1[8];
#pragma unroll
  for (int c = 0; c < 8; ++c) acc1[c] = {0.f, 0.f, 0.f, 0.f};
#pragma unroll
  for (int s = 0; s < 8; ++s) {
#pragma unroll
    for (int c = 0; c < 8; ++c) {
      half4 bf = w1h[(s * 8 + c) * 64 + l];
      acc1[c] = __builtin_amdgcn_mfma_f32_16x16x16f16(af[s], bf, acc1[c], 0, 0, 0);
    }
  }
  __syncthreads();
#pragma unroll
  for (int c = 0; c < 8; ++c) {
    float bb = b1[c * 16 + lr];
#pragma unroll
    for (int r = 0; r < 4; ++r) {
      float x = acc1[c][r] + bb;
      x = x / (1.f + __expf(-x));
      Ah[16 * w + lg * 4 + r][c * 16 + lr] = (_Float16)x;
    }
  }
  __syncthreads();

  half4 hf[8];
#pragma unroll
  for (int s = 0; s < 8; ++s)
    hf[s] = *(const half4*)&Ah[16 * w + lr][s * 16 + lg * 4];

#pragma unroll 1
  for (int cg = 0; cg < 8; ++cg) {
    f32x4 a3[3];
#pragma unroll
    for (int p = 0; p < 3; ++p) a3[p] = {0.f, 0.f, 0.f, 0.f};
#pragma unroll
    for (int s = 0; s < 8; ++s) {
#pragma unroll
      for (int p = 0; p < 3; ++p) {
        half4 bf = w2h[(s * 24 + cg + p * 8) * 64 + l];
        a3[p] = __builtin_amdgcn_mfma_f32_16x16x16f16(hf[s], bf, a3[p], 0, 0, 0);
      }
    }
    const int j = cg * 16 + lr;
    const float bb0 = b2[j], bb1 = b2[j + 128], bb2 = b2[j + 256];
#pragma unroll
    for (int r = 0; r < 4; ++r) {
      int n = row0 + 16 * w + lg * 4 + r;
      if (n >= M) continue;
      const float* vb = nvec + ((size_t)n * FDIM + j) * 3;
      float v0 = vb[0], v1 = vb[1], v2 = vb[2];
      uint* o = bundle + ((size_t)n * FDIM + j) * 3;
      o[0] = packh(a3[0][r] + bb0, a3[1][r] + bb1);
      o[1] = packh(a3[2][r] + bb2, v0);
      o[2] = packh(v1, v2);
    }
  }
}

// ---------------------------------------------------------------------------
// Persistent per-dst accumulation — R10's exact structure (best measured:
// 149 µs). Shift chains intentionally kept; all restructures regressed
// (R7: 196, R8: 181, R11: 192, R12: 180).
// ---------------------------------------------------------------------------
__global__ __launch_bounds__(128) void accum_kernel(
    const uint* __restrict__ rec, const uint* __restrict__ bundle,
    const float* __restrict__ nvec, const float* __restrict__ Wr,
    const float* __restrict__ br, const float* __restrict__ ns,
    const int* __restrict__ offs, const int* __restrict__ eids,
    float* __restrict__ out_s, float* __restrict__ out_v, int Nn) {
  const int j = threadIdx.x;

  h2 wp0[10], wp1[10], wp2[10];
#pragma unroll
  for (int m = 0; m < 10; ++m) {
    wp0[m] = h2{(_Float16)Wr[(2 * m) * 384 + j], (_Float16)Wr[(2 * m + 1) * 384 + j]};
    wp1[m] = h2{(_Float16)Wr[(2 * m) * 384 + 128 + j], (_Float16)Wr[(2 * m + 1) * 384 + 128 + j]};
    wp2[m] = h2{(_Float16)Wr[(2 * m) * 384 + 256 + j], (_Float16)Wr[(2 * m + 1) * 384 + 256 + j]};
  }
  const float brj0 = br[j], brj1 = br[j + 128], brj2 = br[j + 256];

  __shared__ int sh_e[128], sh_pos[128];

#define SLOT(t) ((t) < 128 ? sh_pos[(t)] : (t))
#define LOADREC(R, t)                                                      \
  {                                                                        \
    int su = __builtin_amdgcn_readfirstlane(beg + SLOT(t));                \
    const uint* p = rec + (size_t)(uint)su * 14;                           \
    _Pragma("unroll") for (int w_ = 0; w_ < 13; ++w_) R[w_] = p[w_];       \
  }
#define LOADB(B0, B1, B2, SRC)                                             \
  {                                                                        \
    const uint* p = bundle + ((size_t)(uint)(SRC)*FDIM + j) * 3;           \
    B0 = p[0];                                                             \
    B1 = p[1];                                                             \
    B2 = p[2];                                                             \
  }

  for (int d = blockIdx.x; d < Nn; d += gridDim.x) {
    const int beg = offs[d];
    const int cnt = offs[d + 1] - beg;
    const int m = cnt < 128 ? cnt : 128;
    if (j < m) sh_e[j] = eids[beg + j];
    __syncthreads();
    if (j < m) {  // rank sort by eid (unique) -> slot index of t-th smallest
      int v = sh_e[j];
      int r = 0;
      for (int u = 0; u < m; ++u) r += (sh_e[u] < v);
      sh_pos[r] = j;
    }
    __syncthreads();

    float acc_s = 0.f, av0 = 0.f, av1 = 0.f, av2 = 0.f;

    uint r_cur[13], r_nxt[13];
    uint b0 = 0, b1 = 0, b2 = 0;
    if (cnt > 0) LOADREC(r_cur, 0);
    if (cnt > 1) LOADREC(r_nxt, 1);
    if (cnt > 0) LOADB(b0, b1, b2, (int)r_cur[0]);

    for (int t = 0; t < cnt; ++t) {
      uint nb0 = 0, nb1 = 0, nb2 = 0;
      if (t + 1 < cnt) LOADB(nb0, nb1, nb2, (int)r_nxt[0]);
      uint r_n2[13];
      if (t + 2 < cnt) LOADREC(r_n2, t + 2);

      float rhx = h_lo(r_cur[1]), rhy = h_hi(r_cur[1]);
      float rhz = h_lo(r_cur[2]), cut = h_hi(r_cur[2]);
      float w0 = cut * brj0, w1 = cut * brj1, w2 = cut * brj2;
#pragma unroll
      for (int q = 0; q < 10; ++q) {
        w0 = dot2(r_cur[3 + q], wp0[q], w0);
        w1 = dot2(r_cur[3 + q], wp1[q], w1);
        w2 = dot2(r_cur[3 + q], wp2[q], w2);
      }
      float s1 = h_lo(b0) * w0;
      float s2 = h_hi(b0) * w1;
      float s3 = h_lo(b1) * w2;
      float pv0 = h_hi(b1), pv1 = h_lo(b2), pv2 = h_hi(b2);
      acc_s += s2;
      av0 = fmaf(pv0, s1, fmaf(s3, rhx, av0));
      av1 = fmaf(pv1, s1, fmaf(s3, rhy, av1));
      av2 = fmaf(pv2, s1, fmaf(s3, rhz, av2));

#pragma unroll
      for (int w_ = 0; w_ < 13; ++w_) {
        r_cur[w_] = r_nxt[w_];
        r_nxt[w_] = r_n2[w_];
      }
      b0 = nb0;
      b1 = nb1;
      b2 = nb2;
    }

    out_s[(size_t)d * FDIM + j] = ns[(size_t)d * FDIM + j] + acc_s;
    float* vo = out_v + (size_t)d * 384 + j * 3;
    const float* vi = nvec + (size_t)d * 384 + j * 3;
    vo[0] = vi[0] + av0;
    vo[1] = vi[1] + av1;
    vo[2] = vi[2] + av2;
  }
#undef SLOT
#undef LOADREC
#undef LOADB
}

// ---------------------------------------------------------------------------
extern "C" void kernel_launch(void* const* d_in, const int* in_sizes, int n_in,
                              void* d_out, int out_size, void* d_ws,
                              size_t ws_size, hipStream_t stream) {
  const float* node_scalar = (const float*)d_in[0];
  const float* node_vector = (const float*)d_in[1];
  const float* adj = (const float*)d_in[2];
  const float* W1 = (const float*)d_in[3];
  const float* b1 = (const float*)d_in[4];
  const float* W2 = (const float*)d_in[5];
  const float* b2 = (const float*)d_in[6];
  const float* Wr = (const float*)d_in[7];
  const float* br = (const float*)d_in[8];

  const int N = in_sizes[0] / FDIM;
  const int E = in_sizes[2] / 6;

  float* out = (float*)d_out;
  float* out_s = out;
  float* out_v = out + (size_t)N * FDIM;

  // workspace: bundle | rec(56B/edge, CSR order) | w1h | w2h | counts | offs | cursor | eids
  char* w = (char*)d_ws;
  uint* bundle = (uint*)w;
  size_t off = (size_t)N * FDIM * 12;
  uint* rec = (uint*)(w + off);
  off += (size_t)E * 56;
  _Float16* w1h = (_Float16*)(w + off);
  off += 8 * 8 * 256 * 2;
  _Float16* w2h = (_Float16*)(w + off);
  off += 8 * 24 * 256 * 2;
  int* counts = (int*)(w + off);
  int* offs = counts + N;
  int* cursor = offs + N + 1;
  int* eids = cursor + N;

  // wconv2 also zeroes counts (separate dispatch precedes hist's atomics)
  wconv2<<<(8 * 8 * 256 + 8 * 24 * 256 + 255) / 256, 256, 0, stream>>>(
      W1, W2, w1h, w2h, counts, N);
  hist_kernel<<<(E + 255) / 256, 256, 0, stream>>>(adj, counts, E);
  scan_kernel<<<1, 1024, 0, stream>>>(counts, offs, cursor, N);

  const int GB = (N + 63) / 64;
  const int EB = (E + 255) / 256;
  prep_gemm<<<GB + EB, 256, 0, stream>>>(node_scalar, (const half4*)w1h, b1,
                                         (const half4*)w2h, b2, node_vector,
                                         bundle, N, adj, cursor, eids, rec, E,
                                         GB);

  const int agrid = N < 4096 ? N : 4096;
  accum_kernel<<<agrid, 128, 0, stream>>>(rec, bundle, node_vector, Wr, br,
                                          node_scalar, offs, eids, out_s,
                                          out_v, N);
}